// Round 5
// baseline (26.899 us; speedup 1.0000x reference)
//
#include <hip/hip_runtime.h>

// PatchMMD: x,y are (64,1,64,64) fp32. For pairs (i,j):
//   D(i,j,p,q) = sum_{3x3 window at (p,q)} (A_i - B_j)^2   (VALID -> 62x62)
//   K = exp(-D / (2*(0.5*9)^2)) = exp(-D/40.5)
// out = offdiag_mean(Kxx) - 2*mean(Kxy) + offdiag_mean(Kyy)
//
// Round 5 structure: ZERO LDS / ZERO barriers in the pair kernel.
//  - one WAVE per pair (4 pairs per 256-thread block); lane = 16*strip + colgroup
//  - lane owns a 4-col x 18-row slab: vertical 3-sum slides in registers,
//    horizontal 3-sum via DPP row_shl:1 (col neighbor == lane neighbor)
//  - closed-form sqrt triangular decode (no serial loop)
//  - fp32 wave butterfly partials; fp64 only in the tiny reduce kernel
//  - symmetry: xx/yy only i<j, doubled in the final combine

#define NPAIR_TRI 2016   // 64*63/2
#define NPAIRS    8128   // 2*2016 + 4096

#if __has_builtin(__builtin_amdgcn_exp2f)
#define EXP2F(v) __builtin_amdgcn_exp2f(v)
#else
#define EXP2F(v) __expf((v) * 0.69314718055994530942f)
#endif

// DPP move: 0x101 = row_shl:1 (lane i <- lane i+1 within 16-lane row),
// bound_ctrl -> 0 fill at row boundary (those lanes are poisoned anyway).
template<int CTRL>
__device__ __forceinline__ float dpp_mov_f(float v) {
    int r = __builtin_amdgcn_update_dpp(0, __float_as_int(v), CTRL, 0xf, 0xf, true);
    return __int_as_float(r);
}

__global__ __launch_bounds__(256) void mmd_pair_kernel(
    const float* __restrict__ x, const float* __restrict__ y,
    float* __restrict__ partials)
{
    const int t    = threadIdx.x;
    const int wid  = t >> 6;
    const int lane = t & 63;
    const int pid  = blockIdx.x * 4 + wid;       // 0..8127, exact

    // decode pair: [0,2016) xx i<j; [2016,4032) yy i<j; [4032,8128) xy all
    const float *Abase, *Bbase;
    if (pid < 2 * NPAIR_TRI) {
        const float* base = (pid < NPAIR_TRI) ? x : y;
        int k = (pid < NPAIR_TRI) ? pid : pid - NPAIR_TRI;
        // i = floor((127 - sqrt(127^2 - 8k))/2), with +-1 fixup for fp rounding
        float s = sqrtf(16129.0f - 8.0f * (float)k);
        int i = (int)floorf((127.0f - s) * 0.5f);
        int b = (i * (127 - i)) >> 1;                    // first k of row i
        if (k < b) { --i; b = (i * (127 - i)) >> 1; }
        else { int nb = ((i + 1) * (126 - i)) >> 1; if (k >= nb) { ++i; b = nb; } }
        int j = i + 1 + (k - b);
        Abase = base + i * 4096; Bbase = base + j * 4096;
    } else {
        int e = pid - 2 * NPAIR_TRI;
        Abase = x + (e >> 6) * 4096; Bbase = y + (e & 63) * 4096;
    }

    const float4* __restrict__ A4 = reinterpret_cast<const float4*>(Abase);
    const float4* __restrict__ B4 = reinterpret_cast<const float4*>(Bbase);

    const int rc = lane >> 4;        // row strip 0..3 (output rows 16rc..16rc+15)
    const int g  = lane & 15;        // float4 col group (cols 4g..4g+3)
    const int r0 = rc * 16;
    const bool g15 = (g == 15);

    const float NEG_SCALE = -1.0f / (40.5f * 0.69314718055994530942f);  // exp2 scale
    float acc = 0.0f;
    float h0x=0,h0y=0,h0z=0,h0w=0, h1x=0,h1y=0,h1z=0,h1w=0;

    #pragma unroll
    for (int rr = 0; rr < 18; ++rr) {
        int row  = r0 + rr;                    // 0..65 (>=64 only for rc==3 tail)
        int rowc = (row < 64) ? row : 63;      // clamped load, result masked
        float4 a = A4[rowc * 16 + g];
        float4 b = B4[rowc * 16 + g];
        float dx = a.x - b.x, dy = a.y - b.y, dz = a.z - b.z, dw = a.w - b.w;
        dx *= dx; dy *= dy; dz *= dz; dw *= dw;
        float nx = dpp_mov_f<0x101>(dx);       // next col-group's first two d^2
        float ny = dpp_mov_f<0x101>(dy);
        float s1 = dy + dz;
        float s2 = dw + nx;
        float hx = dx + s1;                    // h at col 4g
        float hy = s1 + dw;                    // 4g+1
        float hz = dz + s2;                    // 4g+2
        float hw = s2 + ny;                    // 4g+3
        if (g15) { hz = 1e30f; hw = 1e30f; }   // cols 62,63 invalid -> exp == 0

        if (rr >= 2) {
            float Dx = (h0x + h1x) + hx;
            float Dy = (h0y + h1y) + hy;
            float Dz = (h0z + h1z) + hz;
            float Dw = (h0w + h1w) + hw;
            float e0 = EXP2F(Dx * NEG_SCALE);
            float e1 = EXP2F(Dy * NEG_SCALE);
            float e2 = EXP2F(Dz * NEG_SCALE);
            float e3 = EXP2F(Dw * NEG_SCALE);
            if (row < 64)                      // output row p=row-2 valid (<62)
                acc += (e0 + e1) + (e2 + e3);
        }
        h0x = h1x; h0y = h1y; h0z = h1z; h0w = h1w;
        h1x = hx;  h1y = hy;  h1z = hz;  h1w = hw;
    }

    // deterministic 64-lane butterfly (fp32; partial err ~1e-4 abs, harmless)
    #pragma unroll
    for (int off = 32; off > 0; off >>= 1)
        acc += __shfl_xor(acc, off);
    if (lane == 0)
        partials[pid] = acc;
}

__global__ __launch_bounds__(256) void mmd_reduce_kernel(
    const float* __restrict__ partials, float* __restrict__ out)
{
    const int t = threadIdx.x;
    double a_off = 0.0, a_xy = 0.0;
    for (int e = t; e < 2 * NPAIR_TRI; e += 256) a_off += (double)partials[e];
    for (int e = t; e < 4096;          e += 256) a_xy  += (double)partials[2 * NPAIR_TRI + e];

    #pragma unroll
    for (int off = 32; off > 0; off >>= 1) {
        a_off += __shfl_xor(a_off, off);
        a_xy  += __shfl_xor(a_xy,  off);
    }
    __shared__ double w[2][4];
    const int lane = t & 63, wid = t >> 6;
    if (lane == 0) { w[0][wid] = a_off; w[1][wid] = a_xy; }
    __syncthreads();
    if (t == 0) {
        double so = w[0][0] + w[0][1] + w[0][2] + w[0][3];   // half of off-diag sums
        double sx = w[1][0] + w[1][1] + w[1][2] + w[1][3];
        const double cnt_off = 64.0 * 63.0 * 62.0 * 62.0;    // N*(N-1)*h*w
        const double cnt_all = 64.0 * 64.0 * 62.0 * 62.0;    // N*N*h*w
        out[0] = (float)(2.0 * so / cnt_off - 2.0 * sx / cnt_all);
    }
}

extern "C" void kernel_launch(void* const* d_in, const int* in_sizes, int n_in,
                              void* d_out, int out_size, void* d_ws, size_t ws_size,
                              hipStream_t stream) {
    const float* x = (const float*)d_in[0];
    const float* y = (const float*)d_in[1];
    float* out = (float*)d_out;
    float* partials = (float*)d_ws;   // 8128 floats = 32.5 KiB

    mmd_pair_kernel<<<NPAIRS / 4, 256, 0, stream>>>(x, y, partials);
    mmd_reduce_kernel<<<1, 256, 0, stream>>>(partials, out);
}